// Round 1
// baseline (102.253 us; speedup 1.0000x reference)
//
#include <hip/hip_runtime.h>

typedef __attribute__((ext_vector_type(8))) _Float16 half8;
typedef __attribute__((ext_vector_type(4))) float f32x4;

#define T_STEPS 24
#define N_NODES 325
#define ROW_STRIDE_T 20800   // N*F elements per t
#define B_STRIDE 499200      // T*N*F elements per b
#define HLAST_OFF 31948800   // B*T*N*H

__device__ __forceinline__ float fsigmoid(float x) {
    return __builtin_amdgcn_rcpf(1.0f + __expf(-x));
}
__device__ __forceinline__ float ftanh_f(float x) {
    return 1.0f - 2.0f * __builtin_amdgcn_rcpf(1.0f + __expf(2.0f * x));
}
__device__ __forceinline__ half8 cvt8(f32x4 a, f32x4 b) {
    half8 r;
    r[0]=(_Float16)a[0]; r[1]=(_Float16)a[1]; r[2]=(_Float16)a[2]; r[3]=(_Float16)a[3];
    r[4]=(_Float16)b[0]; r[5]=(_Float16)b[1]; r[6]=(_Float16)b[2]; r[7]=(_Float16)b[3];
    return r;
}

// One block = 16 rows of the flat (B*N) batch; 4 waves split H into 16-col slices.
// Each wave keeps its 12 weight B-frags in VGPRs, h slice in D-frag registers;
// h is exchanged across waves once per step via padded LDS (A-frag re-formation).
__global__ __launch_bounds__(256) void gru_fused_kernel(
    const float* __restrict__ data,   // [B,T,N,F]
    const float* __restrict__ h0,     // [B,N,H]
    const float* __restrict__ w_ih,   // [192,64]
    const float* __restrict__ w_hh,   // [192,64]
    const float* __restrict__ b_ih,   // [192]
    const float* __restrict__ b_hh,   // [192]
    float* __restrict__ out)          // [B,T,N,H] ++ [B,N,H]
{
    const int lane = threadIdx.x & 63;
    const int wv   = threadIdx.x >> 6;   // 0..3
    const int cl   = lane & 15;          // col-in-tile / A-row
    const int kg   = lane >> 4;          // k-group 0..3
    const int c0   = wv * 16;            // this wave's H-col slice base
    const int row0 = blockIdx.x * 16;

    __shared__ __align__(16) float hbuf[2][16][68];  // +4 pad: ≤2-way banks

    // ---- weight B-fragments (registers, reused all 24 steps) ----
    half8 wih[3][2], whh[3][2];
#pragma unroll
    for (int gate = 0; gate < 3; ++gate) {
#pragma unroll
        for (int s = 0; s < 2; ++s) {
            const int n  = gate * 64 + c0 + cl;
            const int k0 = s * 32 + kg * 8;
            f32x4 a0 = *(const f32x4*)(w_ih + n * 64 + k0);
            f32x4 a1 = *(const f32x4*)(w_ih + n * 64 + k0 + 4);
            wih[gate][s] = cvt8(a0, a1);
            f32x4 b0 = *(const f32x4*)(w_hh + n * 64 + k0);
            f32x4 b1 = *(const f32x4*)(w_hh + n * 64 + k0 + 4);
            whh[gate][s] = cvt8(b0, b1);
        }
    }
    const float bi0 = b_ih[      c0 + cl], bh0 = b_hh[      c0 + cl];
    const float bi1 = b_ih[ 64 + c0 + cl], bh1 = b_hh[ 64 + c0 + cl];
    const float bi2 = b_ih[128 + c0 + cl], bh2 = b_hh[128 + c0 + cl];

    // ---- per-lane row addressing ----
    const int xrow = row0 + cl;                       // row this lane loads x for
    const int xb = xrow / N_NODES, xn = xrow % N_NODES;
    const int xbase = xb * B_STRIDE + xn * 64;        // + t*20800 + k

    int obase[4];   // out element offsets (rows kg*4+r of the tile)
    int hbase[4];   // h0 / h_last offsets
#pragma unroll
    for (int r = 0; r < 4; ++r) {
        const int row = row0 + kg * 4 + r;
        const int b = row / N_NODES, n = row % N_NODES;
        obase[r] = b * B_STRIDE + n * 64 + c0 + cl;
        hbase[r] = row * 64 + c0 + cl;
    }

    // ---- init h (D-frag layout), form first A-frags via LDS ----
    float hreg[4];
#pragma unroll
    for (int r = 0; r < 4; ++r) hreg[r] = h0[hbase[r]];
#pragma unroll
    for (int r = 0; r < 4; ++r) hbuf[0][kg * 4 + r][c0 + cl] = hreg[r];
    __syncthreads();
    half8 ha[2];
#pragma unroll
    for (int s = 0; s < 2; ++s) {
        const float* p = &hbuf[0][cl][s * 32 + kg * 8];
        ha[s] = cvt8(*(const f32x4*)p, *(const f32x4*)(p + 4));
    }

    // ---- x for t=0 ----
    f32x4 xc[4];
#pragma unroll
    for (int s = 0; s < 2; ++s) {
        const float* p = data + xbase + s * 32 + kg * 8;
        xc[2 * s]     = *(const f32x4*)p;
        xc[2 * s + 1] = *(const f32x4*)(p + 4);
    }

    for (int t = 0; t < T_STEPS; ++t) {
        // prefetch next step's x (clamped; hides HBM latency under this step)
        const int tn = (t + 1 < T_STEPS) ? t + 1 : T_STEPS - 1;
        f32x4 xnx[4];
#pragma unroll
        for (int s = 0; s < 2; ++s) {
            const float* p = data + xbase + tn * ROW_STRIDE_T + s * 32 + kg * 8;
            xnx[2 * s]     = *(const f32x4*)p;
            xnx[2 * s + 1] = *(const f32x4*)(p + 4);
        }

        f32x4 gx0 = {0,0,0,0}, gx1 = {0,0,0,0}, gx2 = {0,0,0,0};
        f32x4 gh0 = {0,0,0,0}, gh1 = {0,0,0,0}, gh2 = {0,0,0,0};
#pragma unroll
        for (int s = 0; s < 2; ++s) {
            half8 xa = cvt8(xc[2 * s], xc[2 * s + 1]);
            gx0 = __builtin_amdgcn_mfma_f32_16x16x32_f16(xa,    wih[0][s], gx0, 0, 0, 0);
            gx1 = __builtin_amdgcn_mfma_f32_16x16x32_f16(xa,    wih[1][s], gx1, 0, 0, 0);
            gx2 = __builtin_amdgcn_mfma_f32_16x16x32_f16(xa,    wih[2][s], gx2, 0, 0, 0);
            gh0 = __builtin_amdgcn_mfma_f32_16x16x32_f16(ha[s], whh[0][s], gh0, 0, 0, 0);
            gh1 = __builtin_amdgcn_mfma_f32_16x16x32_f16(ha[s], whh[1][s], gh1, 0, 0, 0);
            gh2 = __builtin_amdgcn_mfma_f32_16x16x32_f16(ha[s], whh[2][s], gh2, 0, 0, 0);
        }

        // gates (fp32): r,z = sigmoid; cand = tanh; convex update
#pragma unroll
        for (int r = 0; r < 4; ++r) {
            const float rg = fsigmoid(gx0[r] + bi0 + gh0[r] + bh0);
            const float zg = fsigmoid(gx1[r] + bi1 + gh1[r] + bh1);
            const float cd = ftanh_f(gx2[r] + bi2 + rg * (gh2[r] + bh2));
            hreg[r] = (1.0f - zg) * cd + zg * hreg[r];
        }

        // write outputs[b, t, n, :] slice
#pragma unroll
        for (int r = 0; r < 4; ++r)
            out[t * ROW_STRIDE_T + obase[r]] = hreg[r];

        // exchange h across waves -> next step's A-frags (double-buffered)
        if (t + 1 < T_STEPS) {
            const int nb = (t + 1) & 1;
#pragma unroll
            for (int r = 0; r < 4; ++r) hbuf[nb][kg * 4 + r][c0 + cl] = hreg[r];
            __syncthreads();
#pragma unroll
            for (int s = 0; s < 2; ++s) {
                const float* p = &hbuf[nb][cl][s * 32 + kg * 8];
                ha[s] = cvt8(*(const f32x4*)p, *(const f32x4*)(p + 4));
            }
        }
#pragma unroll
        for (int i = 0; i < 4; ++i) xc[i] = xnx[i];
    }

    // h_last
#pragma unroll
    for (int r = 0; r < 4; ++r)
        out[HLAST_OFF + hbase[r]] = hreg[r];
}

extern "C" void kernel_launch(void* const* d_in, const int* in_sizes, int n_in,
                              void* d_out, int out_size, void* d_ws, size_t ws_size,
                              hipStream_t stream) {
    // d_in[0] = feature (unused by reference)
    const float* data = (const float*)d_in[1];
    const float* h0   = (const float*)d_in[2];
    const float* w_ih = (const float*)d_in[3];
    const float* w_hh = (const float*)d_in[4];
    const float* b_ih = (const float*)d_in[5];
    const float* b_hh = (const float*)d_in[6];
    float* out = (float*)d_out;

    // 20800 rows / 16 per block = 1300 blocks
    gru_fused_kernel<<<dim3(1300), dim3(256), 0, stream>>>(
        data, h0, w_ih, w_hh, b_ih, b_hh, out);
}

// Round 3
// 99.736 us; speedup vs baseline: 1.0252x; 1.0252x over previous
//
#include <hip/hip_runtime.h>

typedef __attribute__((ext_vector_type(4))) _Float16 half4;
typedef __attribute__((ext_vector_type(4))) float f32x4;

#define T_STEPS 24
#define N_NODES 325
#define RS_T 20800       // N*F elements per t
#define B_STRIDE 499200  // T*N*F elements per b
#define HLAST_OFF 31948800

__device__ __forceinline__ float fsigmoid(float x) {
    return __builtin_amdgcn_rcpf(1.0f + __expf(-x));
}
__device__ __forceinline__ float ftanh_f(float x) {
    return 1.0f - 2.0f * __builtin_amdgcn_rcpf(1.0f + __expf(2.0f * x));
}
__device__ __forceinline__ half4 cvt4(f32x4 a) {
    half4 r;
    r[0] = (_Float16)a[0]; r[1] = (_Float16)a[1];
    r[2] = (_Float16)a[2]; r[3] = (_Float16)a[3];
    return r;
}

// One block = 16 rows of flat (B*N); 4 waves split H into 16-col slices.
// K=16 MFMA so all 24 weight B-frags fit in 48 VGPRs (register-resident).
// Per-step barrier is lgkmcnt-only: x prefetch + out stores stay in flight.
__global__ __launch_bounds__(256, 4) void gru_fused_kernel(
    const float* __restrict__ data,   // [B,T,N,F]
    const float* __restrict__ h0,     // [B,N,H]
    const float* __restrict__ w_ih,   // [192,64]
    const float* __restrict__ w_hh,   // [192,64]
    const float* __restrict__ b_ih,   // [192]
    const float* __restrict__ b_hh,   // [192]
    float* __restrict__ out)          // [B,T,N,H] ++ [B,N,H]
{
    const int lane = threadIdx.x & 63;
    const int wv   = threadIdx.x >> 6;   // 0..3
    const int cl   = lane & 15;          // A-row / B-col / D-col
    const int kg   = lane >> 4;          // k-group 0..3
    const int c0   = wv * 16;            // wave's H-col slice base
    const int row0 = blockIdx.x * 16;

    __shared__ _Float16 hbuf[2][16][72]; // f16 h exchange; 144B row stride

    // ---- weight B-frags: k = s*16 + kg*4 + i (same labeling for A & B) ----
    half4 wih[3][4], whh[3][4];
#pragma unroll
    for (int gate = 0; gate < 3; ++gate) {
#pragma unroll
        for (int s = 0; s < 4; ++s) {
            const int n  = gate * 64 + c0 + cl;
            const int k0 = s * 16 + kg * 4;
            wih[gate][s] = cvt4(*(const f32x4*)(w_ih + n * 64 + k0));
            whh[gate][s] = cvt4(*(const f32x4*)(w_hh + n * 64 + k0));
        }
    }
    const float bc0 = b_ih[      c0 + cl] + b_hh[      c0 + cl]; // r gate
    const float bc1 = b_ih[ 64 + c0 + cl] + b_hh[ 64 + c0 + cl]; // z gate
    const float bi2 = b_ih[128 + c0 + cl];
    const float bh2 = b_hh[128 + c0 + cl];

    // ---- addressing ----
    const int xrow = row0 + cl;
    const int xb = xrow / N_NODES, xn = xrow % N_NODES;
    const int xbase = xb * B_STRIDE + xn * 64;      // + t*RS_T + k

    const int hb0 = (row0 + kg * 4) * 64 + c0 + cl; // + 64*r
    int obase[4];
#pragma unroll
    for (int r = 0; r < 4; ++r) {
        const int row = row0 + kg * 4 + r;
        const int b = row / N_NODES, n = row % N_NODES;
        obase[r] = b * B_STRIDE + n * 64 + c0 + cl;
    }

    // ---- init h (D-frag layout), first A-frags via LDS ----
    float hreg[4];
#pragma unroll
    for (int r = 0; r < 4; ++r) hreg[r] = h0[hb0 + 64 * r];
#pragma unroll
    for (int r = 0; r < 4; ++r)
        hbuf[0][kg * 4 + r][c0 + cl] = (_Float16)hreg[r];
    __syncthreads();
    half4 ha[4];
#pragma unroll
    for (int s = 0; s < 4; ++s)
        ha[s] = *(const half4*)&hbuf[0][cl][s * 16 + kg * 4];

    // ---- x for t=0 (in flight at loop entry) ----
    f32x4 xf[4];
#pragma unroll
    for (int s = 0; s < 4; ++s)
        xf[s] = *(const f32x4*)(data + xbase + s * 16 + kg * 4);

    for (int t = 0; t < T_STEPS; ++t) {
        // arrived x -> f16 A-frags, then reuse xf for next step's prefetch
        half4 xh[4];
#pragma unroll
        for (int s = 0; s < 4; ++s) xh[s] = cvt4(xf[s]);
        const int tn = (t + 1 < T_STEPS) ? t + 1 : T_STEPS - 1;
#pragma unroll
        for (int s = 0; s < 4; ++s)
            xf[s] = *(const f32x4*)(data + xbase + tn * RS_T + s * 16 + kg * 4);

        // GEMMs: r/z gates accumulate x-side and h-side into ONE acc each
        f32x4 a_rz0 = {0,0,0,0}, a_rz1 = {0,0,0,0};
        f32x4 a_gx2 = {0,0,0,0}, a_gh2 = {0,0,0,0};
#pragma unroll
        for (int s = 0; s < 4; ++s) {
            a_rz0 = __builtin_amdgcn_mfma_f32_16x16x16f16(ha[s], whh[0][s], a_rz0, 0, 0, 0);
            a_rz1 = __builtin_amdgcn_mfma_f32_16x16x16f16(ha[s], whh[1][s], a_rz1, 0, 0, 0);
            a_gh2 = __builtin_amdgcn_mfma_f32_16x16x16f16(ha[s], whh[2][s], a_gh2, 0, 0, 0);
            a_rz0 = __builtin_amdgcn_mfma_f32_16x16x16f16(xh[s], wih[0][s], a_rz0, 0, 0, 0);
            a_rz1 = __builtin_amdgcn_mfma_f32_16x16x16f16(xh[s], wih[1][s], a_rz1, 0, 0, 0);
            a_gx2 = __builtin_amdgcn_mfma_f32_16x16x16f16(xh[s], wih[2][s], a_gx2, 0, 0, 0);
        }

        // gates (fp32)
#pragma unroll
        for (int r = 0; r < 4; ++r) {
            const float rg = fsigmoid(a_rz0[r] + bc0);
            const float zg = fsigmoid(a_rz1[r] + bc1);
            const float cd = ftanh_f(a_gx2[r] + bi2 + rg * (a_gh2[r] + bh2));
            hreg[r] = (1.0f - zg) * cd + zg * hreg[r];
        }

        // store outputs (fire-and-forget; never drained by the barrier)
#pragma unroll
        for (int r = 0; r < 4; ++r)
            out[t * RS_T + obase[r]] = hreg[r];

        // cross-wave h exchange, lgkmcnt-only barrier (double-buffered)
        if (t + 1 < T_STEPS) {
            const int nb = (t + 1) & 1;
#pragma unroll
            for (int r = 0; r < 4; ++r)
                hbuf[nb][kg * 4 + r][c0 + cl] = (_Float16)hreg[r];
            asm volatile("s_waitcnt lgkmcnt(0)" ::: "memory");
            __builtin_amdgcn_s_barrier();
            asm volatile("" ::: "memory");
#pragma unroll
            for (int s = 0; s < 4; ++s)
                ha[s] = *(const half4*)&hbuf[nb][cl][s * 16 + kg * 4];
        }
    }

    // h_last
#pragma unroll
    for (int r = 0; r < 4; ++r)
        out[HLAST_OFF + hb0 + 64 * r] = hreg[r];
}

extern "C" void kernel_launch(void* const* d_in, const int* in_sizes, int n_in,
                              void* d_out, int out_size, void* d_ws, size_t ws_size,
                              hipStream_t stream) {
    const float* data = (const float*)d_in[1];
    const float* h0   = (const float*)d_in[2];
    const float* w_ih = (const float*)d_in[3];
    const float* w_hh = (const float*)d_in[4];
    const float* b_ih = (const float*)d_in[5];
    const float* b_hh = (const float*)d_in[6];
    float* out = (float*)d_out;

    gru_fused_kernel<<<dim3(1300), dim3(256), 0, stream>>>(
        data, h0, w_ih, w_hh, b_ih, b_hh, out);
}